// Round 15
// baseline (821.543 us; speedup 1.0000x reference)
//
#include <hip/hip_runtime.h>
#include <stdint.h>

#define INV_T 10.0f
#define SHIFT_ 460.0f
#define MROWS 8192
#define DDIM 1024
#define CHUNK 1024

typedef __attribute__((ext_vector_type(8))) short bf16x8;
typedef __attribute__((ext_vector_type(4))) float f32x4;

__device__ __forceinline__ float bf2f(unsigned short u) {
  return __uint_as_float(((unsigned int)u) << 16);
}
__device__ __forceinline__ unsigned short f2bf(float f) {
  unsigned int u = __float_as_uint(f);
  return (unsigned short)((u + 0x7FFFu + ((u >> 16) & 1u)) >> 16);
}
__device__ __forceinline__ void gl2lds16(const unsigned short* g, unsigned short* l) {
  __builtin_amdgcn_global_load_lds((const __attribute__((address_space(1))) void*)g,
                                   (__attribute__((address_space(3))) void*)l, 16, 0, 0);
}

// ---------------- fused prep+transpose: ONE fp32 read -> bf16 row-major + bf16 transposed + n2 ----------------
__global__ void prepT_kernel(const float* __restrict__ gen, const float* __restrict__ pos,
                             unsigned short* __restrict__ gen_h, unsigned short* __restrict__ pos_h,
                             unsigned short* __restrict__ genT, unsigned short* __restrict__ posT,
                             float* __restrict__ gn2, float* __restrict__ pn2) {
  __shared__ float tile[64][65];
  __shared__ float psum[64][4];
  int b = blockIdx.x;
  const float* src; unsigned short* dstT; unsigned short* dstH; float* n2;
  if (b < 2048) { src = gen; dstT = genT; dstH = gen_h; n2 = gn2; }
  else          { src = pos; dstT = posT; dstH = pos_h; n2 = pn2; b -= 2048; }
  int tj = b >> 4, td = b & 15;
  int t = threadIdx.x;
#pragma unroll
  for (int it = 0; it < 16; ++it) {
    int idx = it * 256 + t;
    int r = idx >> 6, c = idx & 63;
    tile[r][c] = src[(size_t)(tj * 64 + r) * DDIM + td * 64 + c];
  }
  __syncthreads();
  {
    int r4 = t >> 2, q = t & 3;  // 4 threads per row
    float s = 0.f;
#pragma unroll
    for (int i = 0; i < 16; ++i) { float v = tile[r4][q * 16 + i]; s += v * v; }
    psum[r4][q] = s;
  }
#pragma unroll
  for (int it = 0; it < 16; ++it) {
    int idx = it * 256 + t;
    int r = idx >> 6, c = idx & 63;
    dstH[(size_t)(tj * 64 + r) * DDIM + td * 64 + c] = f2bf(tile[r][c]);
  }
#pragma unroll
  for (int it = 0; it < 16; ++it) {
    int idx = it * 256 + t;
    int d = idx >> 6, j = idx & 63;
    dstT[(size_t)(td * 64 + d) * MROWS + tj * 64 + j] = f2bf(tile[j][d]);
  }
  __syncthreads();
  if (t < 64) {
    float s = psum[t][0] + psum[t][1] + psum[t][2] + psum[t][3];
    atomicAdd(&n2[tj * 64 + t], s);
  }
}

// ---------------- score GEMM, width-PAIR (verified round-14 form): 2048 blocks ----------------
__launch_bounds__(256, 2)
__global__ void gemm_sc2(const unsigned short* __restrict__ Aq,
                         const unsigned short* __restrict__ Bpos,  // pos_h base
                         const unsigned short* __restrict__ Bgen,  // gen_h base
                         int j0lo, int j0hi,
                         unsigned short* __restrict__ PaLo, unsigned short* __restrict__ PrLo,
                         unsigned short* __restrict__ PaHi, unsigned short* __restrict__ PrHi,
                         const float* __restrict__ gn2, const float* __restrict__ pn2,
                         float* __restrict__ lsumA, float* __restrict__ lsumR) {
  __shared__ __align__(16) unsigned short Al[128 * 64];
  __shared__ __align__(16) unsigned short Bl[128 * 64];

  // chunked XCD swizzle (nwg=2048, %8==0), y-fastest
  const int orig = blockIdx.x + 64 * (blockIdx.y + 16 * blockIdx.z);
  const int wid = (orig & 7) * 256 + (orig >> 3);
  const int gy = wid & 15;
  const int bx = (wid >> 4) & 63;
  const int z = wid >> 10;
  const int hi = gy >> 3;
  const int by = gy & 7;

  const int j0 = hi ? j0hi : j0lo;
  const unsigned short* B = z ? Bgen : Bpos;
  const float* kn2 = z ? gn2 : pn2;
  float* lsum = z ? lsumR : lsumA;
  unsigned short* Pout = hi ? (z ? PrHi : PaHi) : (z ? PrLo : PaLo);

  const int t = threadIdx.x;
  const int w = t >> 6, lane = t & 63, l15 = lane & 15, quad = lane >> 4;
  const int wm = w >> 1, wn = w & 1;
  const long m0 = (long)bx * 128;
  const long n0 = (long)by * 128;
  const int trow = t >> 3;
  const int tcol = (((t & 7) ^ (trow & 7)) * 8);

  f32x4 acc[4][4];
#pragma unroll
  for (int i = 0; i < 4; ++i)
#pragma unroll
    for (int j = 0; j < 4; ++j) acc[i][j] = (f32x4){0.f, 0.f, 0.f, 0.f};

  const unsigned short* Ab = Aq + (m0 + trow) * DDIM + tcol;
  const unsigned short* Bb = B + ((long)j0 + n0 + trow) * DDIM + tcol;
  unsigned short* Alw = Al + t * 8;
  unsigned short* Blw = Bl + t * 8;
  const int ue = (quad ^ (l15 & 7)) * 8;

  for (int ks = 0; ks < DDIM / 64; ++ks) {
    const long ko = (long)ks * 64;
#pragma unroll
    for (int i = 0; i < 4; ++i) gl2lds16(Ab + (long)i * 32 * DDIM + ko, Alw + i * 2048);
#pragma unroll
    for (int i = 0; i < 4; ++i) gl2lds16(Bb + (long)i * 32 * DDIM + ko, Blw + i * 2048);
    __syncthreads();
#pragma unroll
    for (int kk = 0; kk < 2; ++kk) {
      const int uo = ue ^ (kk * 32);
      bf16x8 af[4], bfr[4];
#pragma unroll
      for (int mi = 0; mi < 4; ++mi)
        af[mi] = *(const bf16x8*)(Al + (wm * 64 + mi * 16 + l15) * 64 + uo);
#pragma unroll
      for (int ni = 0; ni < 4; ++ni)
        bfr[ni] = *(const bf16x8*)(Bl + (wn * 64 + ni * 16 + l15) * 64 + uo);
#pragma unroll
      for (int mi = 0; mi < 4; ++mi)
#pragma unroll
        for (int ni = 0; ni < 4; ++ni)
          acc[mi][ni] = __builtin_amdgcn_mfma_f32_16x16x32_bf16(af[mi], bfr[ni], acc[mi][ni], 0, 0, 0);
    }
    __syncthreads();
  }

#pragma unroll
  for (int mi = 0; mi < 4; ++mi) {
    float rs[4] = {0.f, 0.f, 0.f, 0.f};
#pragma unroll
    for (int ni = 0; ni < 4; ++ni) {
      int c = (int)n0 + wn * 64 + ni * 16 + l15;
      float kn = kn2[j0 + c];
#pragma unroll
      for (int reg = 0; reg < 4; ++reg) {
        long r = m0 + wm * 64 + mi * 16 + quad * 4 + reg;
        float v = acc[mi][ni][reg];
        float d2 = gn2[r] + kn - 2.0f * v;
        float p = __expf(SHIFT_ - INV_T * sqrtf(fmaxf(d2, 0.0f)));
        if (z && (int)r == (j0 + c)) p = 0.0f;
        rs[reg] += p;
        Pout[r * (long)CHUNK + c] = f2bf(p);
      }
    }
#pragma unroll
    for (int reg = 0; reg < 4; ++reg) {
      float v = rs[reg];
      v += __shfl_xor(v, 1); v += __shfl_xor(v, 2);
      v += __shfl_xor(v, 4); v += __shfl_xor(v, 8);
      if (l15 == 0) atomicAdd(&lsum[m0 + wm * 64 + mi * 16 + quad * 4 + reg], v);
    }
  }
}

// ---------------- PV GEMM, pair-fused (verified round-10 form): 32 K-steps/block ----------------
// Pair granularity keeps the P working set at 64 MB -> L3-resident when dispatched right
// after its sc2 producer (quad's 128 MB P measured 161 MB HBM FETCH -> L3 thrash, round 14).
#define KSEG(Abase, Bbase, LDA_, LDB_)                                                     \
  {                                                                                        \
    const unsigned short* Ab_ = (Abase) + (m0 + trow) * (LDA_) + tcol;                     \
    const unsigned short* Bb_ = (Bbase) + (n0 + trow) * (LDB_) + tcol;                     \
    for (int ks = 0; ks < 16; ++ks) {                                                      \
      const long ko = (long)ks * 64;                                                       \
      _Pragma("unroll")                                                                    \
      for (int i = 0; i < 4; ++i) gl2lds16(Ab_ + (long)i * 32 * (LDA_) + ko, Alw + i * 2048); \
      _Pragma("unroll")                                                                    \
      for (int i = 0; i < 4; ++i) gl2lds16(Bb_ + (long)i * 32 * (LDB_) + ko, Blw + i * 2048); \
      __syncthreads();                                                                     \
      _Pragma("unroll")                                                                    \
      for (int kk = 0; kk < 2; ++kk) {                                                     \
        const int uo = ue ^ (kk * 32);                                                     \
        bf16x8 af[4], bfr[4];                                                              \
        _Pragma("unroll")                                                                  \
        for (int mi = 0; mi < 4; ++mi)                                                     \
          af[mi] = *(const bf16x8*)(Al + (wm * 64 + mi * 16 + l15) * 64 + uo);             \
        _Pragma("unroll")                                                                  \
        for (int ni = 0; ni < 4; ++ni)                                                     \
          bfr[ni] = *(const bf16x8*)(Bl + (wn * 64 + ni * 16 + l15) * 64 + uo);            \
        _Pragma("unroll")                                                                  \
        for (int mi = 0; mi < 4; ++mi)                                                     \
          _Pragma("unroll")                                                                \
          for (int ni = 0; ni < 4; ++ni)                                                   \
            acc[mi][ni] = __builtin_amdgcn_mfma_f32_16x16x32_bf16(af[mi], bfr[ni], acc[mi][ni], 0, 0, 0); \
      }                                                                                    \
      __syncthreads();                                                                     \
    }                                                                                      \
  }

__launch_bounds__(256, 2)
__global__ void gemm_pv2(const unsigned short* __restrict__ Pa0, const unsigned short* __restrict__ Pr0,
                         const unsigned short* __restrict__ Pa1, const unsigned short* __restrict__ Pr1,
                         const unsigned short* __restrict__ Va0, const unsigned short* __restrict__ Vr0,
                         const unsigned short* __restrict__ Va1, const unsigned short* __restrict__ Vr1,
                         unsigned short* __restrict__ OA, unsigned short* __restrict__ OR_,
                         int first) {
  __shared__ __align__(16) unsigned short Al[128 * 64];
  __shared__ __align__(16) unsigned short Bl[128 * 64];

  const int orig = blockIdx.x + 64 * (blockIdx.y + 8 * blockIdx.z);
  const int wid = (orig & 7) * 128 + (orig >> 3);  // nwg=1024
  const int by = wid & 7;
  const int bx = (wid >> 3) & 63;
  const int z = wid >> 9;

  const unsigned short* A0 = z ? Pr0 : Pa0;
  const unsigned short* B0 = z ? Vr0 : Va0;
  const unsigned short* A1 = z ? Pr1 : Pa1;
  const unsigned short* B1 = z ? Vr1 : Va1;

  const int t = threadIdx.x;
  const int w = t >> 6, lane = t & 63, l15 = lane & 15, quad = lane >> 4;
  const int wm = w >> 1, wn = w & 1;
  const long m0 = (long)bx * 128;
  const long n0 = (long)by * 128;
  const int trow = t >> 3;
  const int tcol = (((t & 7) ^ (trow & 7)) * 8);

  f32x4 acc[4][4];
#pragma unroll
  for (int i = 0; i < 4; ++i)
#pragma unroll
    for (int j = 0; j < 4; ++j) acc[i][j] = (f32x4){0.f, 0.f, 0.f, 0.f};

  unsigned short* Alw = Al + t * 8;
  unsigned short* Blw = Bl + t * 8;
  const int ue = (quad ^ (l15 & 7)) * 8;

  KSEG(A0, B0, CHUNK, MROWS);
  KSEG(A1, B1, CHUNK, MROWS);

  unsigned short* Oh = z ? OR_ : OA;
#pragma unroll
  for (int mi = 0; mi < 4; ++mi)
#pragma unroll
    for (int ni = 0; ni < 4; ++ni) {
      long c = n0 + wn * 64 + ni * 16 + l15;
#pragma unroll
      for (int reg = 0; reg < 4; ++reg) {
        long r = m0 + wm * 64 + mi * 16 + quad * 4 + reg;
        long off = r * DDIM + c;
        float v = acc[mi][ni][reg];
        Oh[off] = f2bf(first ? v : (bf2f(Oh[off]) + v));
      }
    }
}
#undef KSEG

// ---------------- merged epilogue: all four stats in one pass; 4 atomics/block ----------------
__global__ void epi_kernel(const unsigned short* __restrict__ OA, const unsigned short* __restrict__ OR_,
                           const float* __restrict__ lsumA, const float* __restrict__ lsumR,
                           const float* __restrict__ genf, float* __restrict__ gs) {
  __shared__ float wsL[4], wsD[4], wsA[4], wsR[4];
  const int t = threadIdx.x;
  const int w = t >> 6;
  const int lane = t & 63;
  float accL = 0.f, accD = 0.f, accA = 0.f, accR = 0.f;

  for (int i = 0; i < 8; ++i) {
    const int row = blockIdx.x * 32 + w * 8 + i;
    const float invlA = 1.0f / lsumA[row];
    const float invlR = 1.0f / lsumR[row];
    float ssA = 0.f, ssR = 0.f, ssD = 0.f;
#pragma unroll
    for (int u = 0; u < 4; ++u) {
      const long off = (long)row * DDIM + u * 256 + lane * 4;
      float4 g = *(const float4*)(genf + off);
      ushort4 oa = *(const ushort4*)(OA + off);
      ushort4 orr = *(const ushort4*)(OR_ + off);
      float g4[4] = {g.x, g.y, g.z, g.w};
      float a4[4] = {bf2f(oa.x), bf2f(oa.y), bf2f(oa.z), bf2f(oa.w)};
      float r4[4] = {bf2f(orr.x), bf2f(orr.y), bf2f(orr.z), bf2f(orr.w)};
#pragma unroll
      for (int e = 0; e < 4; ++e) {
        float a_ = a4[e] * invlA - g4[e];
        float r_ = r4[e] * invlR - g4[e];
        float d_ = a_ - r_;
        ssA += a_ * a_; ssR += r_ * r_; ssD += d_ * d_;
      }
    }
#pragma unroll
    for (int m = 1; m < 64; m <<= 1) {
      ssA += __shfl_xor(ssA, m);
      ssR += __shfl_xor(ssR, m);
      ssD += __shfl_xor(ssD, m);
    }
    accA += sqrtf(ssA); accR += sqrtf(ssR); accD += sqrtf(ssD); accL += ssD;
  }
  if (lane == 0) { wsL[w] = accL; wsD[w] = accD; wsA[w] = accA; wsR[w] = accR; }
  __syncthreads();
  if (t == 0) {
    atomicAdd(&gs[0], wsL[0] + wsL[1] + wsL[2] + wsL[3]);
    atomicAdd(&gs[1], wsD[0] + wsD[1] + wsD[2] + wsD[3]);
    atomicAdd(&gs[2], wsA[0] + wsA[1] + wsA[2] + wsA[3]);
    atomicAdd(&gs[3], wsR[0] + wsR[1] + wsR[2] + wsR[3]);
  }
}

__global__ void finalize_kernel(const float* __restrict__ gs, float* __restrict__ out) {
  int t = threadIdx.x;
  if (t == 0) out[0] = gs[0] / (8192.0f * 1024.0f);
  if (t == 1) out[1] = gs[1] / 8192.0f;
  if (t == 2) out[2] = gs[2] / 8192.0f;
  if (t == 3) out[3] = gs[3] / 8192.0f;
}

extern "C" void kernel_launch(void* const* d_in, const int* in_sizes, int n_in,
                              void* d_out, int out_size, void* d_ws, size_t ws_size,
                              hipStream_t stream) {
  const float* gen = (const float*)d_in[0];
  const float* pos = (const float*)d_in[1];
  char* ws = (char*)d_ws;
  const size_t MB = (size_t)1 << 20;

  unsigned short* gen_h = (unsigned short*)(ws + 0 * MB);    // 16 MB
  unsigned short* pos_h = (unsigned short*)(ws + 16 * MB);   // 16 MB
  unsigned short* genT  = (unsigned short*)(ws + 32 * MB);   // 16 MB
  unsigned short* posT  = (unsigned short*)(ws + 48 * MB);   // 16 MB
  unsigned short* Pa0   = (unsigned short*)(ws + 64 * MB);   // 16 MB
  unsigned short* Pr0   = (unsigned short*)(ws + 80 * MB);   // 16 MB
  unsigned short* Pa1   = (unsigned short*)(ws + 96 * MB);   // 16 MB
  unsigned short* Pr1   = (unsigned short*)(ws + 112 * MB);  // 16 MB
  unsigned short* OhA   = (unsigned short*)(ws + 128 * MB);  // 16 MB
  unsigned short* OhR   = (unsigned short*)(ws + 144 * MB);  // 16 MB
  float* gn2   = (float*)(ws + 160 * MB);                    // 32 KB (atomics -> zeroed)
  float* pn2   = (float*)(ws + 160 * MB + 32768);            // 32 KB (atomics -> zeroed)
  float* lsumA = (float*)(ws + 160 * MB + 65536);            // 32 KB
  float* lsumR = (float*)(ws + 160 * MB + 98304);            // 32 KB
  float* gs    = (float*)(ws + 160 * MB + 131072);           // 16 B

  // zero gn2, pn2, lsumA, lsumR, gs in one contiguous memset
  hipMemsetAsync(gn2, 0, 131072 + 16, stream);
  prepT_kernel<<<dim3(4096), dim3(256), 0, stream>>>(gen, pos, gen_h, pos_h, genT, posT, gn2, pn2);

  for (int p = 0; p < 4; ++p) {
    const int c0 = 2 * p;
    gemm_sc2<<<dim3(64, 16, 2), dim3(256), 0, stream>>>(
        gen_h, pos_h, gen_h, c0 * CHUNK, (c0 + 1) * CHUNK,
        Pa0, Pr0, Pa1, Pr1, gn2, pn2, lsumA, lsumR);
    const long j0 = (long)c0 * CHUNK;
    gemm_pv2<<<dim3(64, 8, 2), dim3(256), 0, stream>>>(
        Pa0, Pr0, Pa1, Pr1,
        posT + j0, genT + j0, posT + j0 + CHUNK, genT + j0 + CHUNK,
        OhA, OhR, p == 0);
  }

  epi_kernel<<<dim3(256), dim3(256), 0, stream>>>(OhA, OhR, lsumA, lsumR, gen, gs);
  finalize_kernel<<<dim3(1), dim3(64), 0, stream>>>(gs, (float*)d_out);
}

// Round 16
// 771.492 us; speedup vs baseline: 1.0649x; 1.0649x over previous
//
#include <hip/hip_runtime.h>
#include <stdint.h>

#define INV_T 10.0f
#define SHIFT_ 460.0f
#define MROWS 8192
#define DDIM 1024
#define CHUNK 1024

typedef __attribute__((ext_vector_type(8))) short bf16x8;
typedef __attribute__((ext_vector_type(4))) float f32x4;

__device__ __forceinline__ float bf2f(unsigned short u) {
  return __uint_as_float(((unsigned int)u) << 16);
}
__device__ __forceinline__ unsigned short f2bf(float f) {
  unsigned int u = __float_as_uint(f);
  return (unsigned short)((u + 0x7FFFu + ((u >> 16) & 1u)) >> 16);
}
__device__ __forceinline__ void gl2lds16(const unsigned short* g, unsigned short* l) {
  __builtin_amdgcn_global_load_lds((const __attribute__((address_space(1))) void*)g,
                                   (__attribute__((address_space(3))) void*)l, 16, 0, 0);
}

// ---------------- fused prep+transpose (verified round-14) ----------------
__global__ void prepT_kernel(const float* __restrict__ gen, const float* __restrict__ pos,
                             unsigned short* __restrict__ gen_h, unsigned short* __restrict__ pos_h,
                             unsigned short* __restrict__ genT, unsigned short* __restrict__ posT,
                             float* __restrict__ gn2, float* __restrict__ pn2) {
  __shared__ float tile[64][65];
  __shared__ float psum[64][4];
  int b = blockIdx.x;
  const float* src; unsigned short* dstT; unsigned short* dstH; float* n2;
  if (b < 2048) { src = gen; dstT = genT; dstH = gen_h; n2 = gn2; }
  else          { src = pos; dstT = posT; dstH = pos_h; n2 = pn2; b -= 2048; }
  int tj = b >> 4, td = b & 15;
  int t = threadIdx.x;
#pragma unroll
  for (int it = 0; it < 16; ++it) {
    int idx = it * 256 + t;
    int r = idx >> 6, c = idx & 63;
    tile[r][c] = src[(size_t)(tj * 64 + r) * DDIM + td * 64 + c];
  }
  __syncthreads();
  {
    int r4 = t >> 2, q = t & 3;
    float s = 0.f;
#pragma unroll
    for (int i = 0; i < 16; ++i) { float v = tile[r4][q * 16 + i]; s += v * v; }
    psum[r4][q] = s;
  }
#pragma unroll
  for (int it = 0; it < 16; ++it) {
    int idx = it * 256 + t;
    int r = idx >> 6, c = idx & 63;
    dstH[(size_t)(tj * 64 + r) * DDIM + td * 64 + c] = f2bf(tile[r][c]);
  }
#pragma unroll
  for (int it = 0; it < 16; ++it) {
    int idx = it * 256 + t;
    int d = idx >> 6, j = idx & 63;
    dstT[(size_t)(td * 64 + d) * MROWS + tj * 64 + j] = f2bf(tile[j][d]);
  }
  __syncthreads();
  if (t < 64) {
    float s = psum[t][0] + psum[t][1] + psum[t][2] + psum[t][3];
    atomicAdd(&n2[tj * 64 + t], s);
  }
}

// ---------------- rep score, TRIANGULAR: tile (r,c), r>=c, direct + mirrored write ----------------
// 2080 blocks. Verified K-loop; epilogue adds: LDS-transposed mirror write to Prep[c][r] and
// column-sum atomics (= mirrored row sums) when r!=c. Diag tiles (r==c) masked, no mirror.
__launch_bounds__(256, 2)
__global__ void repsc_tri(const unsigned short* __restrict__ Ah,     // gen_h
                          unsigned short* __restrict__ Prep,         // full [8192][8192] bf16
                          const float* __restrict__ gn2,
                          float* __restrict__ lsumR) {
  __shared__ __align__(16) unsigned short lbuf[128 * 132];  // K-loop: Al=lbuf[0..8191], Bl=+8192; epi: 128x132 tile
  unsigned short* Al = lbuf;
  unsigned short* Bl = lbuf + 128 * 64;

  const int orig = blockIdx.x;
  const int wid = (orig & 7) * 260 + (orig >> 3);   // nwg=2080=8*260, bijective chunked swizzle
  int r = (int)((sqrtf(8.0f * (float)wid + 1.0f) - 1.0f) * 0.5f);
  while ((r + 1) * (r + 2) / 2 <= wid) ++r;
  while (r * (r + 1) / 2 > wid) --r;
  const int c = wid - r * (r + 1) / 2;              // 0 <= c <= r <= 63

  const int t = threadIdx.x;
  const int w = t >> 6, lane = t & 63, l15 = lane & 15, quad = lane >> 4;
  const int wm = w >> 1, wn = w & 1;
  const long m0 = (long)r * 128;
  const long n0 = (long)c * 128;
  const int trow = t >> 3;
  const int tcol = (((t & 7) ^ (trow & 7)) * 8);

  f32x4 acc[4][4];
#pragma unroll
  for (int i = 0; i < 4; ++i)
#pragma unroll
    for (int j = 0; j < 4; ++j) acc[i][j] = (f32x4){0.f, 0.f, 0.f, 0.f};

  const unsigned short* Ab = Ah + (m0 + trow) * DDIM + tcol;
  const unsigned short* Bb = Ah + (n0 + trow) * DDIM + tcol;
  unsigned short* Alw = Al + t * 8;
  unsigned short* Blw = Bl + t * 8;
  const int ue = (quad ^ (l15 & 7)) * 8;

  for (int ks = 0; ks < DDIM / 64; ++ks) {
    const long ko = (long)ks * 64;
#pragma unroll
    for (int i = 0; i < 4; ++i) gl2lds16(Ab + (long)i * 32 * DDIM + ko, Alw + i * 2048);
#pragma unroll
    for (int i = 0; i < 4; ++i) gl2lds16(Bb + (long)i * 32 * DDIM + ko, Blw + i * 2048);
    __syncthreads();
#pragma unroll
    for (int kk = 0; kk < 2; ++kk) {
      const int uo = ue ^ (kk * 32);
      bf16x8 af[4], bfr[4];
#pragma unroll
      for (int mi = 0; mi < 4; ++mi)
        af[mi] = *(const bf16x8*)(Al + (wm * 64 + mi * 16 + l15) * 64 + uo);
#pragma unroll
      for (int ni = 0; ni < 4; ++ni)
        bfr[ni] = *(const bf16x8*)(Bl + (wn * 64 + ni * 16 + l15) * 64 + uo);
#pragma unroll
      for (int mi = 0; mi < 4; ++mi)
#pragma unroll
        for (int ni = 0; ni < 4; ++ni)
          acc[mi][ni] = __builtin_amdgcn_mfma_f32_16x16x32_bf16(af[mi], bfr[ni], acc[mi][ni], 0, 0, 0);
    }
    __syncthreads();
  }

  const bool offd = (r != c);   // block-uniform
  float cs[4] = {0.f, 0.f, 0.f, 0.f};
#pragma unroll
  for (int mi = 0; mi < 4; ++mi) {
    float rs[4] = {0.f, 0.f, 0.f, 0.f};
#pragma unroll
    for (int ni = 0; ni < 4; ++ni) {
      const int colL = wn * 64 + ni * 16 + l15;
      const long col = n0 + colL;
      float kn = gn2[col];
#pragma unroll
      for (int reg = 0; reg < 4; ++reg) {
        const int rowL = wm * 64 + mi * 16 + quad * 4 + reg;
        const long row = m0 + rowL;
        float v = acc[mi][ni][reg];
        float d2 = gn2[row] + kn - 2.0f * v;
        float p = __expf(SHIFT_ - INV_T * sqrtf(fmaxf(d2, 0.0f)));
        if (row == col) p = 0.0f;
        rs[reg] += p;
        cs[ni] += p;
        unsigned short pb = f2bf(p);
        Prep[row * (long)MROWS + col] = pb;
        if (offd) lbuf[rowL * 132 + colL] = pb;
      }
    }
#pragma unroll
    for (int reg = 0; reg < 4; ++reg) {
      float v = rs[reg];
      v += __shfl_xor(v, 1); v += __shfl_xor(v, 2);
      v += __shfl_xor(v, 4); v += __shfl_xor(v, 8);
      if (l15 == 0) atomicAdd(&lsumR[m0 + wm * 64 + mi * 16 + quad * 4 + reg], v);
    }
  }
  if (offd) {
    // column sums -> lsumR[col] (mirrored row sums). Reduce across quad lanes (xor 16, 32).
#pragma unroll
    for (int ni = 0; ni < 4; ++ni) {
      float v = cs[ni];
      v += __shfl_xor(v, 16); v += __shfl_xor(v, 32);
      if (quad == 0) atomicAdd(&lsumR[n0 + wn * 64 + ni * 16 + l15], v);
    }
    __syncthreads();
    // transposed write: Prep[(n0+i)][m0+j..j+3], coalesced ushort4
#pragma unroll
    for (int it = 0; it < 16; ++it) {
      int lin = it * 256 + t;
      int i = lin >> 5, jg = lin & 31, j = jg * 4;
      ushort4 o;
      o.x = lbuf[(j + 0) * 132 + i];
      o.y = lbuf[(j + 1) * 132 + i];
      o.z = lbuf[(j + 2) * 132 + i];
      o.w = lbuf[(j + 3) * 132 + i];
      *(ushort4*)(Prep + (n0 + i) * (long)MROWS + m0 + j) = o;
    }
  }
}

// ---------------- attr score, width-PAIR (sc2 minus z-dim): 1024 blocks ----------------
__launch_bounds__(256, 2)
__global__ void gemm_sca(const unsigned short* __restrict__ Aq,
                         const unsigned short* __restrict__ Bpos,   // pos_h base
                         int j0lo, int j0hi,
                         unsigned short* __restrict__ PaLo, unsigned short* __restrict__ PaHi,
                         const float* __restrict__ gn2, const float* __restrict__ pn2,
                         float* __restrict__ lsumA) {
  __shared__ __align__(16) unsigned short Al[128 * 64];
  __shared__ __align__(16) unsigned short Bl[128 * 64];

  const int orig = blockIdx.x + 64 * blockIdx.y;     // grid (64,16) -> nwg=1024
  const int wid = (orig & 7) * 128 + (orig >> 3);
  const int gy = wid & 15;
  const int bx = (wid >> 4) & 63;
  const int hi = gy >> 3;
  const int by = gy & 7;

  const int j0 = hi ? j0hi : j0lo;
  unsigned short* Pout = hi ? PaHi : PaLo;

  const int t = threadIdx.x;
  const int w = t >> 6, lane = t & 63, l15 = lane & 15, quad = lane >> 4;
  const int wm = w >> 1, wn = w & 1;
  const long m0 = (long)bx * 128;
  const long n0 = (long)by * 128;
  const int trow = t >> 3;
  const int tcol = (((t & 7) ^ (trow & 7)) * 8);

  f32x4 acc[4][4];
#pragma unroll
  for (int i = 0; i < 4; ++i)
#pragma unroll
    for (int j = 0; j < 4; ++j) acc[i][j] = (f32x4){0.f, 0.f, 0.f, 0.f};

  const unsigned short* Ab = Aq + (m0 + trow) * DDIM + tcol;
  const unsigned short* Bb = Bpos + ((long)j0 + n0 + trow) * DDIM + tcol;
  unsigned short* Alw = Al + t * 8;
  unsigned short* Blw = Bl + t * 8;
  const int ue = (quad ^ (l15 & 7)) * 8;

  for (int ks = 0; ks < DDIM / 64; ++ks) {
    const long ko = (long)ks * 64;
#pragma unroll
    for (int i = 0; i < 4; ++i) gl2lds16(Ab + (long)i * 32 * DDIM + ko, Alw + i * 2048);
#pragma unroll
    for (int i = 0; i < 4; ++i) gl2lds16(Bb + (long)i * 32 * DDIM + ko, Blw + i * 2048);
    __syncthreads();
#pragma unroll
    for (int kk = 0; kk < 2; ++kk) {
      const int uo = ue ^ (kk * 32);
      bf16x8 af[4], bfr[4];
#pragma unroll
      for (int mi = 0; mi < 4; ++mi)
        af[mi] = *(const bf16x8*)(Al + (wm * 64 + mi * 16 + l15) * 64 + uo);
#pragma unroll
      for (int ni = 0; ni < 4; ++ni)
        bfr[ni] = *(const bf16x8*)(Bl + (wn * 64 + ni * 16 + l15) * 64 + uo);
#pragma unroll
      for (int mi = 0; mi < 4; ++mi)
#pragma unroll
        for (int ni = 0; ni < 4; ++ni)
          acc[mi][ni] = __builtin_amdgcn_mfma_f32_16x16x32_bf16(af[mi], bfr[ni], acc[mi][ni], 0, 0, 0);
    }
    __syncthreads();
  }

#pragma unroll
  for (int mi = 0; mi < 4; ++mi) {
    float rs[4] = {0.f, 0.f, 0.f, 0.f};
#pragma unroll
    for (int ni = 0; ni < 4; ++ni) {
      int cc = (int)n0 + wn * 64 + ni * 16 + l15;
      float kn = pn2[j0 + cc];
#pragma unroll
      for (int reg = 0; reg < 4; ++reg) {
        long rr = m0 + wm * 64 + mi * 16 + quad * 4 + reg;
        float v = acc[mi][ni][reg];
        float d2 = gn2[rr] + kn - 2.0f * v;
        float p = __expf(SHIFT_ - INV_T * sqrtf(fmaxf(d2, 0.0f)));
        rs[reg] += p;
        Pout[rr * (long)CHUNK + cc] = f2bf(p);
      }
    }
#pragma unroll
    for (int reg = 0; reg < 4; ++reg) {
      float v = rs[reg];
      v += __shfl_xor(v, 1); v += __shfl_xor(v, 2);
      v += __shfl_xor(v, 4); v += __shfl_xor(v, 8);
      if (l15 == 0) atomicAdd(&lsumA[m0 + wm * 64 + mi * 16 + quad * 4 + reg], v);
    }
  }
}

// ---------------- score GEMM, width-PAIR with z streams (verified round-14; FALLBACK path) ----------------
__launch_bounds__(256, 2)
__global__ void gemm_sc2(const unsigned short* __restrict__ Aq,
                         const unsigned short* __restrict__ Bpos,
                         const unsigned short* __restrict__ Bgen,
                         int j0lo, int j0hi,
                         unsigned short* __restrict__ PaLo, unsigned short* __restrict__ PrLo,
                         unsigned short* __restrict__ PaHi, unsigned short* __restrict__ PrHi,
                         const float* __restrict__ gn2, const float* __restrict__ pn2,
                         float* __restrict__ lsumA, float* __restrict__ lsumR) {
  __shared__ __align__(16) unsigned short Al[128 * 64];
  __shared__ __align__(16) unsigned short Bl[128 * 64];

  const int orig = blockIdx.x + 64 * (blockIdx.y + 16 * blockIdx.z);
  const int wid = (orig & 7) * 256 + (orig >> 3);
  const int gy = wid & 15;
  const int bx = (wid >> 4) & 63;
  const int z = wid >> 10;
  const int hi = gy >> 3;
  const int by = gy & 7;

  const int j0 = hi ? j0hi : j0lo;
  const unsigned short* B = z ? Bgen : Bpos;
  const float* kn2 = z ? gn2 : pn2;
  float* lsum = z ? lsumR : lsumA;
  unsigned short* Pout = hi ? (z ? PrHi : PaHi) : (z ? PrLo : PaLo);

  const int t = threadIdx.x;
  const int w = t >> 6, lane = t & 63, l15 = lane & 15, quad = lane >> 4;
  const int wm = w >> 1, wn = w & 1;
  const long m0 = (long)bx * 128;
  const long n0 = (long)by * 128;
  const int trow = t >> 3;
  const int tcol = (((t & 7) ^ (trow & 7)) * 8);

  f32x4 acc[4][4];
#pragma unroll
  for (int i = 0; i < 4; ++i)
#pragma unroll
    for (int j = 0; j < 4; ++j) acc[i][j] = (f32x4){0.f, 0.f, 0.f, 0.f};

  const unsigned short* Ab = Aq + (m0 + trow) * DDIM + tcol;
  const unsigned short* Bb = B + ((long)j0 + n0 + trow) * DDIM + tcol;
  unsigned short* Alw = Al + t * 8;
  unsigned short* Blw = Bl + t * 8;
  const int ue = (quad ^ (l15 & 7)) * 8;

  for (int ks = 0; ks < DDIM / 64; ++ks) {
    const long ko = (long)ks * 64;
#pragma unroll
    for (int i = 0; i < 4; ++i) gl2lds16(Ab + (long)i * 32 * DDIM + ko, Alw + i * 2048);
#pragma unroll
    for (int i = 0; i < 4; ++i) gl2lds16(Bb + (long)i * 32 * DDIM + ko, Blw + i * 2048);
    __syncthreads();
#pragma unroll
    for (int kk = 0; kk < 2; ++kk) {
      const int uo = ue ^ (kk * 32);
      bf16x8 af[4], bfr[4];
#pragma unroll
      for (int mi = 0; mi < 4; ++mi)
        af[mi] = *(const bf16x8*)(Al + (wm * 64 + mi * 16 + l15) * 64 + uo);
#pragma unroll
      for (int ni = 0; ni < 4; ++ni)
        bfr[ni] = *(const bf16x8*)(Bl + (wn * 64 + ni * 16 + l15) * 64 + uo);
#pragma unroll
      for (int mi = 0; mi < 4; ++mi)
#pragma unroll
        for (int ni = 0; ni < 4; ++ni)
          acc[mi][ni] = __builtin_amdgcn_mfma_f32_16x16x32_bf16(af[mi], bfr[ni], acc[mi][ni], 0, 0, 0);
    }
    __syncthreads();
  }

#pragma unroll
  for (int mi = 0; mi < 4; ++mi) {
    float rs[4] = {0.f, 0.f, 0.f, 0.f};
#pragma unroll
    for (int ni = 0; ni < 4; ++ni) {
      int cc = (int)n0 + wn * 64 + ni * 16 + l15;
      float kn = kn2[j0 + cc];
#pragma unroll
      for (int reg = 0; reg < 4; ++reg) {
        long rr = m0 + wm * 64 + mi * 16 + quad * 4 + reg;
        float v = acc[mi][ni][reg];
        float d2 = gn2[rr] + kn - 2.0f * v;
        float p = __expf(SHIFT_ - INV_T * sqrtf(fmaxf(d2, 0.0f)));
        if (z && (int)rr == (j0 + cc)) p = 0.0f;
        rs[reg] += p;
        Pout[rr * (long)CHUNK + cc] = f2bf(p);
      }
    }
#pragma unroll
    for (int reg = 0; reg < 4; ++reg) {
      float v = rs[reg];
      v += __shfl_xor(v, 1); v += __shfl_xor(v, 2);
      v += __shfl_xor(v, 4); v += __shfl_xor(v, 8);
      if (l15 == 0) atomicAdd(&lsum[m0 + wm * 64 + mi * 16 + quad * 4 + reg], v);
    }
  }
}

// ---------------- PV GEMM, quad-fused, generalized rep-A (lda runtime) ----------------
#define KSEG(Abase, LDA_, Bbase)                                                           \
  {                                                                                        \
    const unsigned short* Ab_ = (Abase) + (m0 + trow) * (LDA_) + tcol;                     \
    const unsigned short* Bb_ = (Bbase) + (n0 + trow) * (long)MROWS + tcol;                \
    for (int ks = 0; ks < 16; ++ks) {                                                      \
      const long ko = (long)ks * 64;                                                       \
      _Pragma("unroll")                                                                    \
      for (int i = 0; i < 4; ++i) gl2lds16(Ab_ + (long)i * 32 * (LDA_) + ko, Alw + i * 2048); \
      _Pragma("unroll")                                                                    \
      for (int i = 0; i < 4; ++i) gl2lds16(Bb_ + (long)i * 32 * (long)MROWS + ko, Blw + i * 2048); \
      __syncthreads();                                                                     \
      _Pragma("unroll")                                                                    \
      for (int kk = 0; kk < 2; ++kk) {                                                     \
        const int uo = ue ^ (kk * 32);                                                     \
        bf16x8 af[4], bfr[4];                                                              \
        _Pragma("unroll")                                                                  \
        for (int mi = 0; mi < 4; ++mi)                                                     \
          af[mi] = *(const bf16x8*)(Al + (wm * 64 + mi * 16 + l15) * 64 + uo);             \
        _Pragma("unroll")                                                                  \
        for (int ni = 0; ni < 4; ++ni)                                                     \
          bfr[ni] = *(const bf16x8*)(Bl + (wn * 64 + ni * 16 + l15) * 64 + uo);            \
        _Pragma("unroll")                                                                  \
        for (int mi = 0; mi < 4; ++mi)                                                     \
          _Pragma("unroll")                                                                \
          for (int ni = 0; ni < 4; ++ni)                                                   \
            acc[mi][ni] = __builtin_amdgcn_mfma_f32_16x16x32_bf16(af[mi], bfr[ni], acc[mi][ni], 0, 0, 0); \
      }                                                                                    \
      __syncthreads();                                                                     \
    }                                                                                      \
  }

__launch_bounds__(256, 2)
__global__ void gemm_pvq(const unsigned short* __restrict__ Pa0, const unsigned short* __restrict__ Pa1,
                         const unsigned short* __restrict__ Pa2, const unsigned short* __restrict__ Pa3,
                         const unsigned short* __restrict__ Ra0, const unsigned short* __restrict__ Ra1,
                         const unsigned short* __restrict__ Ra2, const unsigned short* __restrict__ Ra3,
                         long ldaRep,
                         const unsigned short* __restrict__ Vp,   // posT + j0base
                         const unsigned short* __restrict__ Vg,   // genT + j0base
                         unsigned short* __restrict__ OA, unsigned short* __restrict__ OR_,
                         int first) {
  __shared__ __align__(16) unsigned short Al[128 * 64];
  __shared__ __align__(16) unsigned short Bl[128 * 64];

  const int orig = blockIdx.x + 64 * (blockIdx.y + 8 * blockIdx.z);
  const int wid = (orig & 7) * 128 + (orig >> 3);  // nwg=1024
  const int by = wid & 7;
  const int bx = (wid >> 3) & 63;
  const int z = wid >> 9;

  const long ldaA = z ? ldaRep : (long)CHUNK;
  const unsigned short* A0 = z ? Ra0 : Pa0;
  const unsigned short* A1 = z ? Ra1 : Pa1;
  const unsigned short* A2 = z ? Ra2 : Pa2;
  const unsigned short* A3 = z ? Ra3 : Pa3;
  const unsigned short* Vb = z ? Vg : Vp;

  const int t = threadIdx.x;
  const int w = t >> 6, lane = t & 63, l15 = lane & 15, quad = lane >> 4;
  const int wm = w >> 1, wn = w & 1;
  const long m0 = (long)bx * 128;
  const long n0 = (long)by * 128;
  const int trow = t >> 3;
  const int tcol = (((t & 7) ^ (trow & 7)) * 8);

  f32x4 acc[4][4];
#pragma unroll
  for (int i = 0; i < 4; ++i)
#pragma unroll
    for (int j = 0; j < 4; ++j) acc[i][j] = (f32x4){0.f, 0.f, 0.f, 0.f};

  unsigned short* Alw = Al + t * 8;
  unsigned short* Blw = Bl + t * 8;
  const int ue = (quad ^ (l15 & 7)) * 8;

  KSEG(A0, ldaA, Vb + 0 * CHUNK);
  KSEG(A1, ldaA, Vb + 1 * CHUNK);
  KSEG(A2, ldaA, Vb + 2 * CHUNK);
  KSEG(A3, ldaA, Vb + 3 * CHUNK);

  unsigned short* Oh = z ? OR_ : OA;
#pragma unroll
  for (int mi = 0; mi < 4; ++mi)
#pragma unroll
    for (int ni = 0; ni < 4; ++ni) {
      long cc = n0 + wn * 64 + ni * 16 + l15;
#pragma unroll
      for (int reg = 0; reg < 4; ++reg) {
        long rr = m0 + wm * 64 + mi * 16 + quad * 4 + reg;
        long off = rr * DDIM + cc;
        float v = acc[mi][ni][reg];
        Oh[off] = f2bf(first ? v : (bf2f(Oh[off]) + v));
      }
    }
}
#undef KSEG

// ---------------- merged stats epilogue (widened to 1024 blocks) ----------------
__global__ void epi_kernel(const unsigned short* __restrict__ OA, const unsigned short* __restrict__ OR_,
                           const float* __restrict__ lsumA, const float* __restrict__ lsumR,
                           const float* __restrict__ genf, float* __restrict__ gs) {
  __shared__ float wsL[4], wsD[4], wsA[4], wsR[4];
  const int t = threadIdx.x;
  const int w = t >> 6;
  const int lane = t & 63;
  float accL = 0.f, accD = 0.f, accA = 0.f, accR = 0.f;

  for (int i = 0; i < 2; ++i) {
    const int row = blockIdx.x * 8 + w * 2 + i;
    const float invlA = 1.0f / lsumA[row];
    const float invlR = 1.0f / lsumR[row];
    float ssA = 0.f, ssR = 0.f, ssD = 0.f;
#pragma unroll
    for (int u = 0; u < 4; ++u) {
      const long off = (long)row * DDIM + u * 256 + lane * 4;
      float4 g = *(const float4*)(genf + off);
      ushort4 oa = *(const ushort4*)(OA + off);
      ushort4 orr = *(const ushort4*)(OR_ + off);
      float g4[4] = {g.x, g.y, g.z, g.w};
      float a4[4] = {bf2f(oa.x), bf2f(oa.y), bf2f(oa.z), bf2f(oa.w)};
      float r4[4] = {bf2f(orr.x), bf2f(orr.y), bf2f(orr.z), bf2f(orr.w)};
#pragma unroll
      for (int e = 0; e < 4; ++e) {
        float a_ = a4[e] * invlA - g4[e];
        float r_ = r4[e] * invlR - g4[e];
        float d_ = a_ - r_;
        ssA += a_ * a_; ssR += r_ * r_; ssD += d_ * d_;
      }
    }
#pragma unroll
    for (int m = 1; m < 64; m <<= 1) {
      ssA += __shfl_xor(ssA, m);
      ssR += __shfl_xor(ssR, m);
      ssD += __shfl_xor(ssD, m);
    }
    accA += sqrtf(ssA); accR += sqrtf(ssR); accD += sqrtf(ssD); accL += ssD;
  }
  if (lane == 0) { wsL[w] = accL; wsD[w] = accD; wsA[w] = accA; wsR[w] = accR; }
  __syncthreads();
  if (t == 0) {
    atomicAdd(&gs[0], wsL[0] + wsL[1] + wsL[2] + wsL[3]);
    atomicAdd(&gs[1], wsD[0] + wsD[1] + wsD[2] + wsD[3]);
    atomicAdd(&gs[2], wsA[0] + wsA[1] + wsA[2] + wsA[3]);
    atomicAdd(&gs[3], wsR[0] + wsR[1] + wsR[2] + wsR[3]);
  }
}

__global__ void finalize_kernel(const float* __restrict__ gs, float* __restrict__ out) {
  int t = threadIdx.x;
  if (t == 0) out[0] = gs[0] / (8192.0f * 1024.0f);
  if (t == 1) out[1] = gs[1] / 8192.0f;
  if (t == 2) out[2] = gs[2] / 8192.0f;
  if (t == 3) out[3] = gs[3] / 8192.0f;
}

extern "C" void kernel_launch(void* const* d_in, const int* in_sizes, int n_in,
                              void* d_out, int out_size, void* d_ws, size_t ws_size,
                              hipStream_t stream) {
  const float* gen = (const float*)d_in[0];
  const float* pos = (const float*)d_in[1];
  char* ws = (char*)d_ws;
  const size_t MB = (size_t)1 << 20;
  const size_t need_sym = 288 * MB + 131072 + 16;

  unsigned short* gen_h = (unsigned short*)(ws + 0 * MB);    // 16 MB
  unsigned short* pos_h = (unsigned short*)(ws + 16 * MB);   // 16 MB
  unsigned short* genT  = (unsigned short*)(ws + 32 * MB);   // 16 MB
  unsigned short* posT  = (unsigned short*)(ws + 48 * MB);   // 16 MB

  if (ws_size >= need_sym) {
    // -------- symmetric path: tri rep-score into full Prep, attr chunked --------
    unsigned short* Prep = (unsigned short*)(ws + 64 * MB);  // 128 MB full rep P
    unsigned short* Pa[4] = {(unsigned short*)(ws + 192 * MB), (unsigned short*)(ws + 208 * MB),
                             (unsigned short*)(ws + 224 * MB), (unsigned short*)(ws + 240 * MB)};
    unsigned short* OhA = (unsigned short*)(ws + 256 * MB);
    unsigned short* OhR = (unsigned short*)(ws + 272 * MB);
    float* gn2   = (float*)(ws + 288 * MB);
    float* pn2   = (float*)(ws + 288 * MB + 32768);
    float* lsumA = (float*)(ws + 288 * MB + 65536);
    float* lsumR = (float*)(ws + 288 * MB + 98304);
    float* gs    = (float*)(ws + 288 * MB + 131072);

    hipMemsetAsync(gn2, 0, 131072 + 16, stream);
    prepT_kernel<<<dim3(4096), dim3(256), 0, stream>>>(gen, pos, gen_h, pos_h, genT, posT, gn2, pn2);

    repsc_tri<<<dim3(2080), dim3(256), 0, stream>>>(gen_h, Prep, gn2, lsumR);

    for (int p = 0; p < 2; ++p) {
      const int c0 = 4 * p;
      gemm_sca<<<dim3(64, 16), dim3(256), 0, stream>>>(
          gen_h, pos_h, c0 * CHUNK, (c0 + 1) * CHUNK, Pa[0], Pa[1], gn2, pn2, lsumA);
      gemm_sca<<<dim3(64, 16), dim3(256), 0, stream>>>(
          gen_h, pos_h, (c0 + 2) * CHUNK, (c0 + 3) * CHUNK, Pa[2], Pa[3], gn2, pn2, lsumA);
      const long j0 = (long)c0 * CHUNK;
      gemm_pvq<<<dim3(64, 8, 2), dim3(256), 0, stream>>>(
          Pa[0], Pa[1], Pa[2], Pa[3],
          Prep + j0, Prep + j0 + CHUNK, Prep + j0 + 2 * CHUNK, Prep + j0 + 3 * CHUNK,
          (long)MROWS,
          posT + j0, genT + j0,
          OhA, OhR, p == 0);
    }

    epi_kernel<<<dim3(1024), dim3(256), 0, stream>>>(OhA, OhR, lsumA, lsumR, gen, gs);
    finalize_kernel<<<dim3(1), dim3(64), 0, stream>>>(gs, (float*)d_out);
  } else {
    // -------- fallback: exact round-14 schedule (verified 760 us) --------
    unsigned short* Pa[4] = {(unsigned short*)(ws + 64 * MB),  (unsigned short*)(ws + 96 * MB),
                             (unsigned short*)(ws + 128 * MB), (unsigned short*)(ws + 160 * MB)};
    unsigned short* Pr[4] = {(unsigned short*)(ws + 80 * MB),  (unsigned short*)(ws + 112 * MB),
                             (unsigned short*)(ws + 144 * MB), (unsigned short*)(ws + 176 * MB)};
    unsigned short* OhA = (unsigned short*)(ws + 192 * MB);
    unsigned short* OhR = (unsigned short*)(ws + 208 * MB);
    float* gn2   = (float*)(ws + 224 * MB);
    float* pn2   = (float*)(ws + 224 * MB + 32768);
    float* lsumA = (float*)(ws + 224 * MB + 65536);
    float* lsumR = (float*)(ws + 224 * MB + 98304);
    float* gs    = (float*)(ws + 224 * MB + 131072);

    hipMemsetAsync(gn2, 0, 131072 + 16, stream);
    prepT_kernel<<<dim3(4096), dim3(256), 0, stream>>>(gen, pos, gen_h, pos_h, genT, posT, gn2, pn2);

    for (int p = 0; p < 2; ++p) {
      const int c0 = 4 * p;
      gemm_sc2<<<dim3(64, 16, 2), dim3(256), 0, stream>>>(
          gen_h, pos_h, gen_h, c0 * CHUNK, (c0 + 1) * CHUNK,
          Pa[0], Pr[0], Pa[1], Pr[1], gn2, pn2, lsumA, lsumR);
      gemm_sc2<<<dim3(64, 16, 2), dim3(256), 0, stream>>>(
          gen_h, pos_h, gen_h, (c0 + 2) * CHUNK, (c0 + 3) * CHUNK,
          Pa[2], Pr[2], Pa[3], Pr[3], gn2, pn2, lsumA, lsumR);
      const long j0 = (long)c0 * CHUNK;
      gemm_pvq<<<dim3(64, 8, 2), dim3(256), 0, stream>>>(
          Pa[0], Pa[1], Pa[2], Pa[3],
          Pr[0], Pr[1], Pr[2], Pr[3],
          (long)CHUNK,
          posT + j0, genT + j0,
          OhA, OhR, p == 0);
    }

    epi_kernel<<<dim3(1024), dim3(256), 0, stream>>>(OhA, OhR, lsumA, lsumR, gen, gs);
    finalize_kernel<<<dim3(1), dim3(64), 0, stream>>>(gs, (float*)d_out);
  }
}